// Round 4
// baseline (16.579 us; speedup 1.0000x reference)
//
#include <hip/hip_runtime.h>
#include <hip/hip_bf16.h>

// out[i, d] = W[d, idx[i]] + b[d]   (one-hot(idx) @ W^T + b)
// Phase 1: Wt[c][d] = W[d][c] + b[d]  (vectorized LDS transpose, bias fused)
// Phase 2: out[i][:] = Wt[idx[i]][:]  (coalesced row copy, nt stores)

typedef float f32x4 __attribute__((ext_vector_type(4)));  // clang vector: ok for nt builtins

// ---- Phase 1: 64c x 32d tile per block, 256 threads ----
__global__ void __launch_bounds__(256) transpose_bias_v2(
    const float* __restrict__ W,     // [EMB][ENV]
    const float* __restrict__ bias,  // [EMB]
    float* __restrict__ Wt,          // [ENV][EMB]
    int ENV, int EMB) {
    __shared__ float tile[32][65];   // [d_local][c_local], pad 65 -> <=2-way banks
    const int c0 = blockIdx.x * 64;
    const int d0 = blockIdx.y * 32;
    const int t  = threadIdx.x;

    // Load: 2 x float4 along c per thread (wave reads 4 rows x 256B)
    #pragma unroll
    for (int k = 0; k < 2; ++k) {
        int f  = t + k * 256;
        int dl = f >> 4;             // 0..31
        int cq = f & 15;             // 0..15
        f32x4 v = *reinterpret_cast<const f32x4*>(
            &W[(size_t)(d0 + dl) * ENV + c0 + cq * 4]);
        tile[dl][cq * 4 + 0] = v.x;
        tile[dl][cq * 4 + 1] = v.y;
        tile[dl][cq * 4 + 2] = v.z;
        tile[dl][cq * 4 + 3] = v.w;
    }
    __syncthreads();

    // Store: 2 x float4 along d per thread, bias fused
    #pragma unroll
    for (int k = 0; k < 2; ++k) {
        int f  = t + k * 256;
        int cl = f >> 3;             // 0..63
        int dq = f & 7;              // 0..7
        f32x4 bv = *reinterpret_cast<const f32x4*>(&bias[d0 + dq * 4]);
        f32x4 o;
        o.x = tile[dq * 4 + 0][cl] + bv.x;
        o.y = tile[dq * 4 + 1][cl] + bv.y;
        o.z = tile[dq * 4 + 2][cl] + bv.z;
        o.w = tile[dq * 4 + 3][cl] + bv.w;
        *reinterpret_cast<f32x4*>(&Wt[(size_t)(c0 + cl) * EMB + d0 + dq * 4]) = o;
    }
}

// ---- Phase 2: 16 threads/row, 32B/lane, nt stores ----
template <int EMB4>  // float4s per row (32 for EMB=128)
__global__ void __launch_bounds__(256) gather_v2(
    const int* __restrict__ idx,
    const f32x4* __restrict__ Wt4,   // [ENV][EMB4], bias fused
    f32x4* __restrict__ out4,        // [B][EMB4]
    int B) {
    constexpr int TPR = EMB4 / 2;    // threads per row, 2 float4 each
    int t = blockIdx.x * blockDim.x + threadIdx.x;
    int i = t / TPR;                 // constexpr pow2 -> shift
    if (i >= B) return;
    int g = (t % TPR) * 2;
    int c = idx[i];
    const f32x4* src = &Wt4[(size_t)c * EMB4 + g];
    f32x4 v0 = src[0];
    f32x4 v1 = src[1];
    f32x4* dst = &out4[(size_t)i * EMB4 + g];
    __builtin_nontemporal_store(v0, dst + 0);
    __builtin_nontemporal_store(v1, dst + 1);
}

// ---- Fallback: direct gather (any shape) ----
__global__ void __launch_bounds__(256) onehot_linear_direct_kernel(
    const int* __restrict__ idx, const float* __restrict__ W,
    const float* __restrict__ bias, float* __restrict__ out,
    int B, int ENV, int EMB) {
    int total = B * EMB;
    for (int t = blockIdx.x * blockDim.x + threadIdx.x; t < total;
         t += gridDim.x * blockDim.x) {
        int i = t / EMB;
        int d = t - i * EMB;
        int c = idx[i];
        out[t] = W[(size_t)d * ENV + c] + bias[d];
    }
}

extern "C" void kernel_launch(void* const* d_in, const int* in_sizes, int n_in,
                              void* d_out, int out_size, void* d_ws, size_t ws_size,
                              hipStream_t stream) {
    const int*   idx  = (const int*)d_in[0];
    const float* W    = (const float*)d_in[1];
    const float* bias = (const float*)d_in[2];
    float*       out  = (float*)d_out;

    const int B   = in_sizes[0];
    const int EMB = in_sizes[2];
    const int ENV = in_sizes[1] / EMB;

    const size_t wt_bytes = (size_t)ENV * EMB * sizeof(float);
    const bool fast = (EMB == 128) && (ENV % 64 == 0) && (ws_size >= wt_bytes) &&
                      (B % 16 == 0);

    if (fast) {
        float* Wt = (float*)d_ws;

        dim3 tg(ENV / 64, EMB / 32);     // (128, 4) = 512 blocks
        transpose_bias_v2<<<tg, 256, 0, stream>>>(W, bias, Wt, ENV, EMB);

        constexpr int EMB4 = 32;
        const int total = B * (EMB4 / 2);            // 16384*16 = 262144
        const int grid  = (total + 255) / 256;       // 1024 blocks
        gather_v2<EMB4><<<grid, 256, 0, stream>>>(
            idx, (const f32x4*)Wt, (f32x4*)out, B);
    } else {
        const int total = B * EMB;
        const int block = 256;
        const int grid  = min((total + block - 1) / block, 2048);
        onehot_linear_direct_kernel<<<grid, block, 0, stream>>>(
            idx, W, bias, out, B, ENV, EMB);
    }
}

// Round 5
// 15.000 us; speedup vs baseline: 1.1053x; 1.1053x over previous
//
#include <hip/hip_runtime.h>
#include <hip/hip_bf16.h>

// out[i, d] = W[d, idx[i]] + b[d]   (one-hot(idx) @ W^T + b)
// Single-dispatch owner-computes: block k owns env columns [32k, 32k+32).
//   A) stage W[:, c0:c0+32] + bias into LDS, transposed  (coalesced f32x4)
//   B) scan idx (int4, L2-resident), build LDS list of matching rows
//   C) waves drain list: out[i][:] = tile[idx[i]-c0][:]  (coalesced stores)

typedef float f32x4 __attribute__((ext_vector_type(4)));
typedef int   i32x4 __attribute__((ext_vector_type(4)));

#define CBLK  32      // env columns per block
#define TSTR  129     // tile stride (129 mod 32 == 1 -> <=2-way banks everywhere)
#define CHUNK 4096    // idx ints per scan chunk (list can never overflow)

__global__ void __launch_bounds__(256) onehot_fused_kernel(
    const int* __restrict__ idx,
    const float* __restrict__ W,     // [128][ENV]
    const float* __restrict__ bias,  // [128]
    float* __restrict__ out,         // [B][128]
    int B, int ENV) {
    __shared__ float tile[CBLK * TSTR];   // tile[cl*TSTR + d] = W[d][c0+cl] + b[d]
    __shared__ int   list[CHUNK];
    __shared__ int   cnt;

    const int t  = threadIdx.x;
    const int c0 = blockIdx.x * CBLK;

    // Phase A: 128 rows x 32 cols; thread (d=t>>3 + 32k, q=t&7) loads 16B of row d.
    #pragma unroll
    for (int k = 0; k < 4; ++k) {
        int d = (t >> 3) + k * 32;
        int q = t & 7;
        f32x4 v = *reinterpret_cast<const f32x4*>(&W[(size_t)d * ENV + c0 + q * 4]);
        float bv = bias[d];
        tile[(q * 4 + 0) * TSTR + d] = v.x + bv;
        tile[(q * 4 + 1) * TSTR + d] = v.y + bv;
        tile[(q * 4 + 2) * TSTR + d] = v.z + bv;
        tile[(q * 4 + 3) * TSTR + d] = v.w + bv;
    }

    const int wave = t >> 6;
    const int lane = t & 63;
    const i32x4* idx4 = reinterpret_cast<const i32x4*>(idx);

    for (int base = 0; base < B; base += CHUNK) {
        if (t == 0) cnt = 0;
        __syncthreads();                       // covers Phase A on first iter

        // Phase B: scan this chunk of idx
        int nq = (min(CHUNK, B - base)) >> 2;  // int4s in chunk
        for (int q = t; q < nq; q += 256) {
            i32x4 v = idx4[((size_t)base >> 2) + q];
            int i0 = base + q * 4;
            #pragma unroll
            for (int j = 0; j < 4; ++j) {
                int cl = v[j] - c0;
                if ((unsigned)cl < (unsigned)CBLK) {
                    int p = atomicAdd(&cnt, 1);
                    list[p] = ((i0 + j) << 5) | cl;
                }
            }
        }
        __syncthreads();

        // Phase C: each wave copies rows; 64 lanes -> two 256B coalesced stores
        int n = cnt;
        for (int r = wave; r < n; r += 4) {
            int e  = list[r];
            int cl = e & 31;
            int i  = e >> 5;
            float v0 = tile[cl * TSTR + lane];
            float v1 = tile[cl * TSTR + 64 + lane];
            float* op = &out[(size_t)i * 128];
            op[lane]      = v0;
            op[lane + 64] = v1;
        }
        __syncthreads();
    }
}

// Fallback for unexpected shapes: direct gather.
__global__ void __launch_bounds__(256) onehot_linear_direct_kernel(
    const int* __restrict__ idx, const float* __restrict__ W,
    const float* __restrict__ bias, float* __restrict__ out,
    int B, int ENV, int EMB) {
    int total = B * EMB;
    for (int t = blockIdx.x * blockDim.x + threadIdx.x; t < total;
         t += gridDim.x * blockDim.x) {
        int i = t / EMB;
        int d = t - i * EMB;
        int c = idx[i];
        out[t] = W[(size_t)d * ENV + c] + bias[d];
    }
}

extern "C" void kernel_launch(void* const* d_in, const int* in_sizes, int n_in,
                              void* d_out, int out_size, void* d_ws, size_t ws_size,
                              hipStream_t stream) {
    const int*   idx  = (const int*)d_in[0];
    const float* W    = (const float*)d_in[1];
    const float* bias = (const float*)d_in[2];
    float*       out  = (float*)d_out;

    const int B   = in_sizes[0];
    const int EMB = in_sizes[2];
    const int ENV = in_sizes[1] / EMB;

    const bool fast = (EMB == 128) && (ENV % CBLK == 0) && (B % 4 == 0);

    if (fast) {
        const int grid = ENV / CBLK;   // 256 blocks, one per column block
        onehot_fused_kernel<<<grid, 256, 0, stream>>>(idx, W, bias, out, B, ENV);
    } else {
        const int total = B * EMB;
        const int block = 256;
        const int grid  = min((total + block - 1) / block, 2048);
        onehot_linear_direct_kernel<<<grid, block, 0, stream>>>(
            idx, W, bias, out, B, ENV, EMB);
    }
}

// Round 6
// 10.495 us; speedup vs baseline: 1.5796x; 1.4292x over previous
//
#include <hip/hip_runtime.h>
#include <hip/hip_bf16.h>

// out[i, d] = W[d, idx[i]] + b[d]   (one-hot(idx) @ W^T + b)
// Single-dispatch owner-computes, v2: block k owns env columns [32k, 32k+32).
//   A) stage W[:, c0:c0+32] + bias into LDS transposed (1 float4/thread)
//   B) scan idx (int4, L2-resident), LDS match-list (atomicAdd, ~64 hits/blk)
//   C) waves drain list: out[i][:] = tile[idx[i]-c0][:]  (float2/lane, 512B/wave)
// 1024 thr/block = 16 waves/CU (was 4); CHUNK=8192 -> 2 scan iterations.

typedef float f32x4 __attribute__((ext_vector_type(4)));
typedef int   i32x4 __attribute__((ext_vector_type(4)));

#define CBLK  32      // env columns per block
#define TSTR  129     // tile stride: 129 % 32 == 1 -> <=2-way banks everywhere
#define CHUNK 8192    // idx ints per scan chunk (list can never overflow)

__global__ void __launch_bounds__(1024) onehot_fused_v2(
    const int* __restrict__ idx,
    const float* __restrict__ W,     // [128][ENV]
    const float* __restrict__ bias,  // [128]
    float* __restrict__ out,         // [B][128]
    int B, int ENV) {
    __shared__ float tile[CBLK * TSTR];   // 16.5 KB
    __shared__ int   list[CHUNK];         // 32 KB
    __shared__ int   cnt;

    const int t  = threadIdx.x;
    const int c0 = blockIdx.x * CBLK;

    // Phase A: one float4 per thread. d = t>>3 (0..127), q = t&7 (8 x 4 cols).
    {
        int d = t >> 3;
        int q = t & 7;
        f32x4 v = *reinterpret_cast<const f32x4*>(
            &W[(size_t)d * ENV + c0 + q * 4]);
        float bv = bias[d];
        tile[(q * 4 + 0) * TSTR + d] = v.x + bv;
        tile[(q * 4 + 1) * TSTR + d] = v.y + bv;
        tile[(q * 4 + 2) * TSTR + d] = v.z + bv;
        tile[(q * 4 + 3) * TSTR + d] = v.w + bv;
    }

    const int wave = t >> 6;
    const int lane = t & 63;
    const i32x4* idx4 = reinterpret_cast<const i32x4*>(idx);

    for (int base = 0; base < B; base += CHUNK) {
        if (t == 0) cnt = 0;
        __syncthreads();                       // tile ready (iter 0) + cnt reset

        // Phase B: scan this chunk of idx
        int nq = (min(CHUNK, B - base)) >> 2;  // int4s in chunk
        for (int q = t; q < nq; q += 1024) {
            i32x4 v = idx4[((size_t)base >> 2) + q];
            int i0 = base + q * 4;
            #pragma unroll
            for (int j = 0; j < 4; ++j) {
                int cl = v[j] - c0;
                if ((unsigned)cl < (unsigned)CBLK) {
                    int p = atomicAdd(&cnt, 1);
                    list[p] = ((i0 + j) << 5) | cl;
                }
            }
        }
        __syncthreads();

        // Phase C: one row per wave-iteration, float2 per lane (512B store)
        int n = cnt;
        for (int r = wave; r < n; r += 16) {
            int e  = list[r];
            int cl = e & 31;
            int i  = e >> 5;
            float2 val;
            val.x = tile[cl * TSTR + 2 * lane];
            val.y = tile[cl * TSTR + 2 * lane + 1];
            *reinterpret_cast<float2*>(&out[(size_t)i * 128 + 2 * lane]) = val;
        }
        __syncthreads();                       // drain before next cnt reset
    }
}

// Fallback for unexpected shapes: direct gather.
__global__ void __launch_bounds__(256) onehot_linear_direct_kernel(
    const int* __restrict__ idx, const float* __restrict__ W,
    const float* __restrict__ bias, float* __restrict__ out,
    int B, int ENV, int EMB) {
    int total = B * EMB;
    for (int t = blockIdx.x * blockDim.x + threadIdx.x; t < total;
         t += gridDim.x * blockDim.x) {
        int i = t / EMB;
        int d = t - i * EMB;
        int c = idx[i];
        out[t] = W[(size_t)d * ENV + c] + bias[d];
    }
}

extern "C" void kernel_launch(void* const* d_in, const int* in_sizes, int n_in,
                              void* d_out, int out_size, void* d_ws, size_t ws_size,
                              hipStream_t stream) {
    const int*   idx  = (const int*)d_in[0];
    const float* W    = (const float*)d_in[1];
    const float* bias = (const float*)d_in[2];
    float*       out  = (float*)d_out;

    const int B   = in_sizes[0];
    const int EMB = in_sizes[2];
    const int ENV = in_sizes[1] / EMB;

    const bool fast = (EMB == 128) && (ENV % CBLK == 0) && (B % 4 == 0);

    if (fast) {
        const int grid = ENV / CBLK;   // 256 blocks, one per column block
        onehot_fused_v2<<<grid, 1024, 0, stream>>>(idx, W, bias, out, B, ENV);
    } else {
        const int total = B * EMB;
        const int block = 256;
        const int grid  = min((total + block - 1) / block, 2048);
        onehot_linear_direct_kernel<<<grid, block, 0, stream>>>(
            idx, W, bias, out, B, ENV, EMB);
    }
}